// Round 7
// baseline (611.018 us; speedup 1.0000x reference)
//
#include <hip/hip_runtime.h>
#include <hip/hip_bf16.h>

// HalfEdgeConv: out[E,256] = relu(concat(x[idx[e,0..3]]) @ W[512,256] + b)
// bf16 split-precision MFMA (Ah*Bh + Ah*Bl + Al*Bh). Round 7: depth-3
// reg-staged pipeline. Loads for step s+3 issued at step s (global->reg),
// reg->LDS ds_write just-in-time, raw s_barrier + lgkmcnt(0) only (no vmcnt
// drain) so gather loads stay in flight across 2 barriers. XCD-paired block
// remap so both N-halves of an M-block (identical gathers) share L2/L3.

#define E_ROWS 262144
#define C_IN   128
#define KN     4
#define O_OUT  256
#define BM     128
#define BN     128
#define BK     32
#define NSTEPS 16
#define NT     512    // 8 waves: 4(M) x 2(N); wave tile 32x64

typedef __attribute__((ext_vector_type(8))) short bf16x8;
typedef __attribute__((ext_vector_type(4))) float f32x4;

__device__ __forceinline__ unsigned short bf16_rne(float f) {
    unsigned u = __float_as_uint(f);
    return (unsigned short)((u + 0x7fffu + ((u >> 16) & 1u)) >> 16);
}

// Coalesced W prep (unchanged from r6). Image layout (uint4 units):
//   wimg[nb*16384 + (2*s+h)*512 + cl], nl=cl>>2, cs=cl&3,
//   source k-chunk c = cs ^ ((nl>>1)&3), chunk = 8 k's of col n=nb*128+nl.
__global__ void prep_w(const float* __restrict__ W, uint4* __restrict__ wimg) {
    __shared__ float Ws[32][260];
    const int s = blockIdx.x;
    const int t = threadIdx.x;
    #pragma unroll
    for (int i = 0; i < 8; ++i) {
        int v4 = i * 256 + t;
        int k  = v4 >> 6;
        int n4 = v4 & 63;
        float4 w = ((const float4*)W)[(size_t)(s * 32 + k) * 64 + n4];
        *(float4*)&Ws[k][n4 * 4] = w;
    }
    __syncthreads();
    #pragma unroll
    for (int i = 0; i < 8; ++i) {
        int q  = i * 256 + t;
        int nb = q >> 10;
        int h  = (q >> 9) & 1;
        int cl = q & 511;
        int nl = cl >> 2;
        int cs = cl & 3;
        int c  = cs ^ ((nl >> 1) & 3);
        int n  = nb * 128 + nl;
        int kb = c * 8;
        unsigned short v[8];
        #pragma unroll
        for (int e = 0; e < 8; ++e) {
            float w = Ws[kb + e][n];
            unsigned u  = __float_as_uint(w);
            unsigned hb = (u + 0x7fffu + ((u >> 16) & 1u)) & 0xffff0000u;
            float r = w - __uint_as_float(hb);
            v[e] = h ? bf16_rne(r) : (unsigned short)(hb >> 16);
        }
        uint4 o;
        o.x = (unsigned)v[0] | ((unsigned)v[1] << 16);
        o.y = (unsigned)v[2] | ((unsigned)v[3] << 16);
        o.z = (unsigned)v[4] | ((unsigned)v[5] << 16);
        o.w = (unsigned)v[6] | ((unsigned)v[7] << 16);
        wimg[(size_t)nb * 16384 + (size_t)(2 * s + h) * 512 + cl] = o;
    }
}

// Issue batch S into reg slot SL (literal 0/1). 4 x global_load_dwordx4.
#define ISSUE(S, SL) do {                                                   \
    int j_  = (S) >> 2;                                                     \
    int kc_ = ((S) & 3) << 5;                                               \
    int i0_ = (j_ & 2) ? ((j_ & 1) ? ib0_3 : ib0_2)                         \
                       : ((j_ & 1) ? ib0_1 : ib0_0);                        \
    int i1_ = (j_ & 2) ? ((j_ & 1) ? ib1_3 : ib1_2)                         \
                       : ((j_ & 1) ? ib1_1 : ib1_0);                        \
    rA0_##SL = *(const uint4*)(x + (size_t)i0_ * C_IN + kc_ + (ac0 << 2));  \
    rA1_##SL = *(const uint4*)(x + (size_t)i1_ * C_IN + kc_ + (ac0 << 2));  \
    const uint4* wp_ = wbase + (size_t)(2 * (S)) * 512 + t;                 \
    rBH_##SL = wp_[0];                                                      \
    rBL_##SL = wp_[512];                                                    \
} while (0)

// Write reg slot SL into LDS buffer PW (parity). 4 x ds_write_b128.
// Compiler inserts the counted vmcnt wait for this slot's loads here.
#define WRITEB(SL, PW) do {                                                 \
    char* Ab_ = Aall + ((PW) << 14);                                        \
    char* Bb_ = Ball + ((PW) << 14);                                        \
    *(uint4*)(Ab_ + t * 16)        = rA0_##SL;                              \
    *(uint4*)(Ab_ + 8192 + t * 16) = rA1_##SL;                              \
    *(uint4*)(Bb_ + t * 16)        = rBH_##SL;                              \
    *(uint4*)(Bb_ + 8192 + t * 16) = rBL_##SL;                              \
} while (0)

#define BARRIER() do {                                                      \
    asm volatile("s_waitcnt lgkmcnt(0)" ::: "memory");                      \
    __builtin_amdgcn_s_barrier();                                           \
} while (0)

__global__ __launch_bounds__(NT, 4) void gemm(
    const float* __restrict__ x,
    const int* __restrict__ nidx,
    const uint4* __restrict__ wimg,
    const float* __restrict__ bias,
    float* __restrict__ out)
{
    __shared__ __align__(16) float A_s[2][BM * BK];              // 2 x 16 KB
    __shared__ __align__(16) unsigned short B_s[2][2 * BN * BK]; // 2 x 16 KB
    __shared__ float b_s[BN];

    const int t = threadIdx.x;

    // XCD-pairing remap: blocks (m,0) and (m,1) land on the same XCD,
    // 8 dispatch slots apart -> second one's gather hits L2/L3.
    const int L    = blockIdx.x + blockIdx.y * 2048;
    const int mblk = (L & 7) | ((L >> 4) << 3);
    const int nb   = (L >> 3) & 1;
    const int m0   = mblk * BM;
    const int n0   = nb * BN;

    if (t < BN) b_s[t] = bias[n0 + t];

    const int l   = t & 63;
    const int wid = t >> 6;     // 0..7
    const int wm  = wid >> 1;   // 0..3 (M)
    const int wn  = wid & 1;    // 0..1 (N)
    const int lr  = l & 15;
    const int lg  = l >> 4;

    // A staging geometry: thread stages chunks q=t and q=512+t.
    // Stored pos cs=q&7 of row q>>3 holds source chunk c = cs ^ (row&7).
    const int arow0 = t >> 3;           // 0..63
    const int ac0   = (t & 7) ^ (arow0 & 7);   // same for row+64

    // neighbor indices in registers (compile-time-indexed scalars)
    const int ib0_0 = nidx[(size_t)(m0 + arow0) * KN + 0];
    const int ib0_1 = nidx[(size_t)(m0 + arow0) * KN + 1];
    const int ib0_2 = nidx[(size_t)(m0 + arow0) * KN + 2];
    const int ib0_3 = nidx[(size_t)(m0 + arow0) * KN + 3];
    const int ib1_0 = nidx[(size_t)(m0 + 64 + arow0) * KN + 0];
    const int ib1_1 = nidx[(size_t)(m0 + 64 + arow0) * KN + 1];
    const int ib1_2 = nidx[(size_t)(m0 + 64 + arow0) * KN + 2];
    const int ib1_3 = nidx[(size_t)(m0 + 64 + arow0) * KN + 3];

    const uint4* wbase = wimg + (size_t)nb * 16384;

    f32x4 acc[2][4];
    #pragma unroll
    for (int i = 0; i < 2; ++i)
        #pragma unroll
        for (int jj = 0; jj < 4; ++jj)
            acc[i][jj] = (f32x4){0.f, 0.f, 0.f, 0.f};

    char* Aall = (char*)&A_s[0][0];
    char* Ball = (char*)&B_s[0][0];

    uint4 rA0_0, rA1_0, rBH_0, rBL_0;   // slot 0: even batches
    uint4 rA0_1, rA1_1, rBH_1, rBL_1;   // slot 1: odd batches

    // ds_read fragments from buffer parity p, split fp32->bf16 hi/lo, 24 MFMA.
    auto COMPUTE = [&](int p) {
        char* Ab = Aall + (p << 14);
        char* Bb = Ball + (p << 14);
        bf16x8 bh[4], bl[4];
        #pragma unroll
        for (int nf = 0; nf < 4; ++nf) {
            int nl  = (wn << 6) + (nf << 4) + lr;
            int cB  = lg ^ ((nl >> 1) & 3);
            int off = nl * 64 + cB * 16;
            bh[nf] = *(const bf16x8*)(Bb + off);
            bl[nf] = *(const bf16x8*)(Bb + 8192 + off);
        }
        #pragma unroll
        for (int mf = 0; mf < 2; ++mf) {
            int row = (wm << 5) + (mf << 4) + lr;
            int c0  = (lg << 1) ^ (row & 7);
            f32x4 a0 = *(const f32x4*)(Ab + row * 128 + c0 * 16);
            f32x4 a1 = *(const f32x4*)(Ab + row * 128 + (c0 ^ 1) * 16);
            float av[8];
            av[0]=a0[0]; av[1]=a0[1]; av[2]=a0[2]; av[3]=a0[3];
            av[4]=a1[0]; av[5]=a1[1]; av[6]=a1[2]; av[7]=a1[3];
            bf16x8 ah, al;
            #pragma unroll
            for (int e = 0; e < 8; ++e) {
                unsigned u  = __float_as_uint(av[e]);
                unsigned hb = u & 0xffff0000u;        // truncated hi (exact split)
                ah[e] = (short)(u >> 16);
                al[e] = (short)bf16_rne(av[e] - __uint_as_float(hb));
            }
            #pragma unroll
            for (int nf = 0; nf < 4; ++nf) {
                acc[mf][nf] = __builtin_amdgcn_mfma_f32_16x16x32_bf16(ah, bh[nf], acc[mf][nf], 0, 0, 0);
                acc[mf][nf] = __builtin_amdgcn_mfma_f32_16x16x32_bf16(ah, bl[nf], acc[mf][nf], 0, 0, 0);
                acc[mf][nf] = __builtin_amdgcn_mfma_f32_16x16x32_bf16(al, bh[nf], acc[mf][nf], 0, 0, 0);
            }
        }
    };

    // ---- prologue: batches 0,1,2 in flight; batch0 written to lds[0] ----
    ISSUE(0, 0);
    ISSUE(1, 1);
    WRITEB(0, 0);          // waits batch0 only (counted), keeps batch1 flying
    ISSUE(2, 0);
    BARRIER();             // lds[0] ready; batches 1,2 still in flight

    // ---- main loop: compute s, write s+1, issue s+3 ----
    #pragma unroll 1
    for (int s = 0; s < 12; s += 2) {
        WRITEB(1, 1);      // batch s+1 -> lds[1]
        ISSUE(s + 3, 1);
        COMPUTE(0);        // step s
        BARRIER();
        WRITEB(0, 0);      // batch s+2 -> lds[0]
        ISSUE(s + 4, 0);
        COMPUTE(1);        // step s+1
        BARRIER();
    }
    // ---- peeled tail: steps 12..15 ----
    WRITEB(1, 1); ISSUE(15, 1); COMPUTE(0); BARRIER();   // s=12 (batch13->lds1)
    WRITEB(0, 0);               COMPUTE(1); BARRIER();   // s=13 (batch14->lds0)
    WRITEB(1, 1);               COMPUTE(0); BARRIER();   // s=14 (batch15->lds1)
    COMPUTE(1);                                          // s=15

    // ---- epilogue: bias + relu; D layout col=lane&15, row=(lane>>4)*4+r ----
    #pragma unroll
    for (int mf = 0; mf < 2; ++mf) {
        #pragma unroll
        for (int nf = 0; nf < 4; ++nf) {
            int colL = (wn << 6) + (nf << 4) + lr;
            int col  = n0 + colL;
            float bv = b_s[colL];
            int rowb = m0 + (wm << 5) + (mf << 4) + (lg << 2);
            #pragma unroll
            for (int r = 0; r < 4; ++r) {
                float v = acc[mf][nf][r] + bv;
                out[(size_t)(rowb + r) * O_OUT + col] = fmaxf(v, 0.f);
            }
        }
    }
}

extern "C" void kernel_launch(void* const* d_in, const int* in_sizes, int n_in,
                              void* d_out, int out_size, void* d_ws, size_t ws_size,
                              hipStream_t stream) {
    const float* x    = (const float*)d_in[0];
    const int*   nidx = (const int*)d_in[1];
    const float* W    = (const float*)d_in[2];
    const float* bias = (const float*)d_in[3];
    float* out  = (float*)d_out;
    uint4* wimg = (uint4*)d_ws;   // 512 KB of ws

    hipLaunchKernelGGL(prep_w, dim3(NSTEPS), dim3(256), 0, stream, W, wimg);
    hipLaunchKernelGGL(gemm, dim3(2048, 2), dim3(NT), 0, stream,
                       x, nidx, wimg, bias, out);
}